// Round 7
// baseline (23.006 us; speedup 1.0000x reference)
//
#include <hip/hip_runtime.h>

// Rank IGR Loss — ONE kernel, HIERARCHICAL fence-free atomic tail.
//
// Ladder so far: R4 (1024 fences) tail ~20us; R6 (flat 512-way election on
// one line + bulk readback) tail ~10us. This round: 2-level election —
// 32 adds on each of 16 per-batch counters (parallel lines), batch-lead
// reads 32x3 slots, publishes 1 triple; final election among 16 leads.
// All cross-block data moves via device-scope atomics (atomicExch publish,
// atomicOr(.,0) read) — coherent across XCDs, validated absmax 0.0 in R6.
// Counters are __device__ globals: 0 at load, reset by the final block each
// run (self-restoring; immune to ws poisoning; no memset node).
//
// Math (validated R3-R6): per-block sorted 64-elem j-tile by
// d' = pos ? d : -1e30 (ties by index), inclusive suffix sums of
// w1=e^{G1 p}, w2=e^{G2 iou}; per i a 6-probe lower_bound with the EXACT
// brute-force f32 predicate (d_j - d_i >= 1.0f, monotone in d_j) + one
// suffix lookup. Non-pos j sort to the front, never reached; non-pos i have
// v1=v2=0. Double partials; fixed reduction order -> deterministic.

#define G1 3.0f
#define G2 1.0f

constexpr int B    = 16;
constexpr int N    = 2048;
constexpr int TJ   = 64;          // sorted j-tile per block
constexpr int IPT  = 8;           // i per thread (full N i-strip per block)
constexpr int JCH  = N / TJ;      // 32 blocks per batch
constexpr int NBLK = B * JCH;     // 512

__device__ unsigned g_cnt_b[B];   // per-batch arrival counters (self-reset)
__device__ unsigned g_cnt_f;      // batch-lead arrival counter (self-reset)

__global__ void __launch_bounds__(256)
igr_kernel(const float* __restrict__ cls, const int* __restrict__ label_cls,
           const float* __restrict__ label_loc, const float* __restrict__ pred,
           const float* __restrict__ tgt, const int* __restrict__ dataset_id,
           double* __restrict__ part, double* __restrict__ bres,
           float* __restrict__ out) {
  __shared__ uint4  stile[TJ];            // {ordkey(d'), idx, w1 bits, w2 bits}
  __shared__ float  ssd[TJ];
  __shared__ float  suf1[TJ + 1], suf2[TJ + 1];
  __shared__ double red[3][4];
  __shared__ unsigned s_lead, s_final;

  const int bid  = blockIdx.x;
  const int b    = bid >> 5;              // / JCH
  const int jc   = bid & 31;
  const int t    = threadIdx.x;
  const int base = b * N;

  const float tx1 = tgt[b * 4 + 0], ty1 = tgt[b * 4 + 1];
  const float tx2 = tgt[b * 4 + 2], ty2 = tgt[b * 4 + 3];
  const float ta  = (tx2 - tx1) * (ty2 - ty1);
  const float tcx = (tx1 + tx2) * 0.5f, tcy = (ty1 + ty2) * 0.5f;

  const float* __restrict__ pb = pred      + (size_t)b * 4 * N;
  const float* __restrict__ lb = label_loc + (size_t)b * 4 * N;

  // ---- stage j tile (wave 0, scalar path — 64 lanes only) ----
  float dm_j = 0.f; unsigned uj = 0u;
  if (t < TJ) {
    const int n = jc * TJ + t;
    float x1 = pb[n], y1 = pb[N + n], x2 = pb[2 * N + n], y2 = pb[3 * N + n];
    float ww = fmaxf(fminf(tx2, x2) - fmaxf(tx1, x1), 0.f);
    float hh = fmaxf(fminf(ty2, y2) - fmaxf(ty1, y1), 0.f);
    float inter = ww * hh;
    float iou  = inter / ((x2 - x1) * (y2 - y1) + ta - inter);
    float prob = __expf(cls[((size_t)(base + n)) * 2 + 1]);
    bool  pos  = label_cls[base + n] > 0;
    float cx = lb[n] + tx1, cy = lb[N + n] + ty1;
    float dx = cx - tcx, dy = cy - tcy;
    float d  = sqrtf(dx * dx + dy * dy);
    dm_j = pos ? d : -1e30f;
    uj = __float_as_uint(dm_j);
    uj ^= (uj & 0x80000000u) ? 0xFFFFFFFFu : 0x80000000u;   // order-preserving
    stile[t] = make_uint4(uj, (unsigned)t,
                          __float_as_uint(__expf(G1 * prob)),
                          __float_as_uint(__expf(G2 * iou)));
  }
  if (t == TJ) { suf1[TJ] = 0.f; suf2[TJ] = 0.f; }

  // ---- per-thread i data: thread t owns n in {4w..4w+3}, w = h*256+t ----
  // float4/int4 loads: 9 wide loads per half instead of 32 scalar.
  const float4* __restrict__ pb4 = (const float4*)pb;
  const float4* __restrict__ lb4 = (const float4*)lb;
  const float4* __restrict__ cl4 = (const float4*)(cls + (size_t)base * 2);
  const int4*   __restrict__ lc4 = (const int4*)(label_cls + base);

  float di[IPT], v1i[IPT], v2i[IPT];
#pragma unroll
  for (int h = 0; h < 2; ++h) {
    const int w = h * 256 + t;
    const float4 X1 = pb4[0 * (N / 4) + w];
    const float4 Y1 = pb4[1 * (N / 4) + w];
    const float4 X2 = pb4[2 * (N / 4) + w];
    const float4 Y2 = pb4[3 * (N / 4) + w];
    const float4 CX = lb4[0 * (N / 4) + w];
    const float4 CY = lb4[1 * (N / 4) + w];
    const float4 C0 = cl4[2 * w + 0];        // cls floats 8w..8w+3; [.,1] = .y/.w
    const float4 C1 = cl4[2 * w + 1];
    const int4   LC = lc4[w];
    const float x1v[4] = {X1.x, X1.y, X1.z, X1.w};
    const float y1v[4] = {Y1.x, Y1.y, Y1.z, Y1.w};
    const float x2v[4] = {X2.x, X2.y, X2.z, X2.w};
    const float y2v[4] = {Y2.x, Y2.y, Y2.z, Y2.w};
    const float cxv[4] = {CX.x, CX.y, CX.z, CX.w};
    const float cyv[4] = {CY.x, CY.y, CY.z, CY.w};
    const float clv[4] = {C0.y, C0.w, C1.y, C1.w};
    const int   lcv[4] = {LC.x, LC.y, LC.z, LC.w};
#pragma unroll
    for (int c = 0; c < 4; ++c) {
      const int k = h * 4 + c;
      float x1 = x1v[c], y1 = y1v[c], x2 = x2v[c], y2 = y2v[c];
      float ww = fmaxf(fminf(tx2, x2) - fmaxf(tx1, x1), 0.f);
      float hh = fmaxf(fminf(ty2, y2) - fmaxf(ty1, y1), 0.f);
      float inter = ww * hh;
      float iou  = inter / ((x2 - x1) * (y2 - y1) + ta - inter);
      float prob = __expf(clv[c]);
      bool  pos  = lcv[c] > 0;
      float cx = cxv[c] + tx1, cy = cyv[c] + ty1;
      float dx = cx - tcx, dy = cy - tcy;
      di[k]  = sqrtf(dx * dx + dy * dy);
      v1i[k] = pos ? __expf(-G1 * prob) : 0.f;   // >0 iff pos
      v2i[k] = pos ? __expf(-G2 * iou)  : 0.f;
    }
  }
  __syncthreads();

  // ---- rank-sort + inclusive suffix sums (wave 0) ----
  if (t < TJ) {
    const unsigned long long mykey = ((unsigned long long)uj << 32) | (unsigned)t;
    int rank = 0; float s1 = 0.f, s2 = 0.f;
#pragma unroll 8
    for (int q = 0; q < TJ; ++q) {
      uint4 v = stile[q];                      // LDS broadcast
      unsigned long long kq = ((unsigned long long)v.x << 32) | v.y;
      bool lt = kq < mykey;
      rank += lt ? 1 : 0;
      s1 += lt ? 0.f : __uint_as_float(v.z);
      s2 += lt ? 0.f : __uint_as_float(v.w);
    }
    ssd[rank] = dm_j; suf1[rank] = s1; suf2[rank] = s2;    // bijective fill
  }
  __syncthreads();

  // ---- 8 binary searches + suffix lookups (exact monotone f32 predicate) ----
  double p1 = 0.0, p2 = 0.0; int cnt = 0;
#pragma unroll
  for (int k = 0; k < IPT; ++k) {
    const float d = di[k];
    int kk = 0;
#pragma unroll
    for (int w = TJ >> 1; w > 0; w >>= 1)
      kk += (ssd[kk + w - 1] - d >= 1.0f) ? 0 : w;
    kk += (ssd[kk] - d >= 1.0f) ? 0 : 1;       // kk in [0, TJ]
    p1 += (double)v1i[k] * (double)suf1[kk];
    p2 += (double)v2i[k] * (double)suf2[kk];
    cnt += (v1i[k] > 0.f) ? (TJ - kk) : 0;
  }
  double pc = (double)cnt;

  for (int off = 32; off; off >>= 1) {
    p1 += __shfl_down(p1, off);
    p2 += __shfl_down(p2, off);
    pc += __shfl_down(pc, off);
  }
  const int wv = t >> 6, lane = t & 63;
  if (lane == 0) { red[0][wv] = p1; red[1][wv] = p2; red[2][wv] = pc; }
  __syncthreads();

  // ---- level 1: publish block partial, elect per-batch lead ----
  if (t == 0) {
    double a = red[0][0] + red[0][1] + red[0][2] + red[0][3];
    double c = red[1][0] + red[1][1] + red[1][2] + red[1][3];
    double e = red[2][0] + red[2][1] + red[2][2] + red[2][3];
    unsigned long long* pp = (unsigned long long*)(part + (size_t)bid * 3);
    unsigned long long o0 = atomicExch(pp + 0, __double_as_longlong(a));
    unsigned long long o1 = atomicExch(pp + 1, __double_as_longlong(c));
    unsigned long long o2 = atomicExch(pp + 2, __double_as_longlong(e));
    asm volatile("" :: "v"(o0), "v"(o1), "v"(o2));  // ack exchanges before elect
    unsigned old = atomicAdd(&g_cnt_b[b], 1u);
    s_lead = (old == (unsigned)(JCH - 1)) ? 1u : 0u;
  }
  __syncthreads();

  if (s_lead) {                                // uniform (shared flag)
    // ---- level 2: batch-lead reduces its 32 partials ----
    double q1 = 0, q2 = 0, qc = 0;
    if (t < JCH) {                             // lanes 0..31 of wave 0
      unsigned long long* pp =
          (unsigned long long*)(part + (size_t)(b * JCH + t) * 3);
      q1 = __longlong_as_double(atomicOr(pp + 0, 0ull));   // coherent read
      q2 = __longlong_as_double(atomicOr(pp + 1, 0ull));
      qc = __longlong_as_double(atomicOr(pp + 2, 0ull));
    }
    for (int off = 16; off; off >>= 1) {       // lanes >=32 contribute zeros
      q1 += __shfl_down(q1, off);
      q2 += __shfl_down(q2, off);
      qc += __shfl_down(qc, off);
    }
    if (t == 0) {
      bool valid = (dataset_id[b] != 1) && (qc > 0.0);
      double denom = fmax(qc, 1.0);
      double l1 = valid ? q1 / denom : 0.0;
      double l2 = valid ? q2 / denom : 0.0;
      double vv = valid ? 1.0 : 0.0;
      unsigned long long* rp = (unsigned long long*)(bres + (size_t)b * 3);
      unsigned long long r0 = atomicExch(rp + 0, __double_as_longlong(l1));
      unsigned long long r1 = atomicExch(rp + 1, __double_as_longlong(l2));
      unsigned long long r2 = atomicExch(rp + 2, __double_as_longlong(vv));
      asm volatile("" :: "v"(r0), "v"(r1), "v"(r2));
      unsigned old2 = atomicAdd(&g_cnt_f, 1u);
      s_final = (old2 == (unsigned)(B - 1)) ? 1u : 0u;
    }
    __syncthreads();

    if (s_final) {                             // uniform (shared flag)
      // ---- level 3: final block reduces 16 batch triples ----
      double r1 = 0, r2 = 0, rv = 0;
      if (t < B) {                             // lanes 0..15 of wave 0
        unsigned long long* rp = (unsigned long long*)(bres + (size_t)t * 3);
        r1 = __longlong_as_double(atomicOr(rp + 0, 0ull));
        r2 = __longlong_as_double(atomicOr(rp + 1, 0ull));
        rv = __longlong_as_double(atomicOr(rp + 2, 0ull));
      }
      for (int off = 8; off; off >>= 1) {
        r1 += __shfl_down(r1, off);
        r2 += __shfl_down(r2, off);
        rv += __shfl_down(rv, off);
      }
      if (t == 0) {
        out[0] = (float)((rv > 0) ? r1 / rv : 0.0);
        out[1] = (float)((rv > 0) ? r2 / rv : 0.0);
        atomicExch(&g_cnt_f, 0u);              // self-reset for next run
      }
      if (t < B) atomicExch(&g_cnt_b[t], 0u);  // all blocks already counted
    }
  }
}

extern "C" void kernel_launch(void* const* d_in, const int* in_sizes, int n_in,
                              void* d_out, int out_size, void* d_ws, size_t ws_size,
                              hipStream_t stream) {
  const float* cls       = (const float*)d_in[0];
  const int*   label_cls = (const int*)d_in[1];
  const float* label_loc = (const float*)d_in[2];
  const float* pred      = (const float*)d_in[3];
  const float* tgt       = (const float*)d_in[4];
  const int*   dset      = (const int*)d_in[5];

  double* part = (double*)d_ws;                       // 512*3 doubles = 12 KB
  double* bres = part + (size_t)NBLK * 3;             // 16*3 doubles
  // every slot is atomically written each run before any read -> poison-safe

  igr_kernel<<<NBLK, 256, 0, stream>>>(cls, label_cls, label_loc, pred, tgt,
                                       dset, part, bres, (float*)d_out);
}

// Round 8
// 18.975 us; speedup vs baseline: 1.2125x; 1.2125x over previous
//
#include <hip/hip_runtime.h>

// Rank IGR Loss — FINAL FORM: two kernels, stream-ordered, no device-scope
// sync. Ladder evidence: compute ~2-3us, graph-node overhead ~6us/node, and
// every in-kernel cross-block tail costs MORE than the node it saves
// (R4 fences ~20us, R6 flat atomics ~10us, R7 hierarchical ~13us). So the
// 2-node structure is the floor for this harness.
//
// K1 (512 blocks): per-block sorted 64-elem j-tile by d' = pos ? d : -1e30
//   (ties by index), inclusive suffix sums of w1=e^{G1 p}, w2=e^{G2 iou};
//   each thread binary-searches for its 8 i-elems with the EXACT brute-force
//   f32 predicate (d_j - d_i >= 1.0f, monotone in d_j) + one suffix lookup.
//   Non-pos j sort to the front, never reached; non-pos i have v1=v2=0.
//   i-loads vectorized float4/int4 (R7-validated layout).
// K2 (1 block): reduce 32 double-triples per batch, batch-mean valid ones.
// Double partials, fixed reduction order -> deterministic (absmax 0.0 R3-R7).

#define G1 3.0f
#define G2 1.0f

constexpr int B    = 16;
constexpr int N    = 2048;
constexpr int TJ   = 64;          // sorted j-tile per block
constexpr int IPT  = 8;           // i per thread (full N i-strip per block)
constexpr int JCH  = N / TJ;      // 32 blocks per batch
constexpr int NBLK = B * JCH;     // 512

__global__ void __launch_bounds__(256)
pair_kernel(const float* __restrict__ cls, const int* __restrict__ label_cls,
            const float* __restrict__ label_loc, const float* __restrict__ pred,
            const float* __restrict__ tgt, double* __restrict__ part) {
  __shared__ uint4  stile[TJ];            // {ordkey(d'), idx, w1 bits, w2 bits}
  __shared__ float  ssd[TJ];
  __shared__ float  suf1[TJ + 1], suf2[TJ + 1];
  __shared__ double red[3][4];

  const int bid  = blockIdx.x;
  const int b    = bid >> 5;              // / JCH
  const int jc   = bid & 31;
  const int t    = threadIdx.x;
  const int base = b * N;

  const float tx1 = tgt[b * 4 + 0], ty1 = tgt[b * 4 + 1];
  const float tx2 = tgt[b * 4 + 2], ty2 = tgt[b * 4 + 3];
  const float ta  = (tx2 - tx1) * (ty2 - ty1);
  const float tcx = (tx1 + tx2) * 0.5f, tcy = (ty1 + ty2) * 0.5f;

  const float* __restrict__ pb = pred      + (size_t)b * 4 * N;
  const float* __restrict__ lb = label_loc + (size_t)b * 4 * N;

  // ---- stage j tile (wave 0, 64 lanes) ----
  float dm_j = 0.f; unsigned uj = 0u;
  if (t < TJ) {
    const int n = jc * TJ + t;
    float x1 = pb[n], y1 = pb[N + n], x2 = pb[2 * N + n], y2 = pb[3 * N + n];
    float ww = fmaxf(fminf(tx2, x2) - fmaxf(tx1, x1), 0.f);
    float hh = fmaxf(fminf(ty2, y2) - fmaxf(ty1, y1), 0.f);
    float inter = ww * hh;
    float iou  = inter / ((x2 - x1) * (y2 - y1) + ta - inter);
    float prob = __expf(cls[((size_t)(base + n)) * 2 + 1]);
    bool  pos  = label_cls[base + n] > 0;
    float cx = lb[n] + tx1, cy = lb[N + n] + ty1;
    float dx = cx - tcx, dy = cy - tcy;
    float d  = sqrtf(dx * dx + dy * dy);
    dm_j = pos ? d : -1e30f;               // !pos can never satisfy cond
    uj = __float_as_uint(dm_j);
    uj ^= (uj & 0x80000000u) ? 0xFFFFFFFFu : 0x80000000u;   // order-preserving
    stile[t] = make_uint4(uj, (unsigned)t,
                          __float_as_uint(__expf(G1 * prob)),
                          __float_as_uint(__expf(G2 * iou)));
  }
  if (t == TJ) { suf1[TJ] = 0.f; suf2[TJ] = 0.f; }

  // ---- per-thread i data: thread t owns n in {4w..4w+3}, w = h*256+t ----
  const float4* __restrict__ pb4 = (const float4*)pb;
  const float4* __restrict__ lb4 = (const float4*)lb;
  const float4* __restrict__ cl4 = (const float4*)(cls + (size_t)base * 2);
  const int4*   __restrict__ lc4 = (const int4*)(label_cls + base);

  float di[IPT], v1i[IPT], v2i[IPT];
#pragma unroll
  for (int h = 0; h < 2; ++h) {
    const int w = h * 256 + t;
    const float4 X1 = pb4[0 * (N / 4) + w];
    const float4 Y1 = pb4[1 * (N / 4) + w];
    const float4 X2 = pb4[2 * (N / 4) + w];
    const float4 Y2 = pb4[3 * (N / 4) + w];
    const float4 CX = lb4[0 * (N / 4) + w];
    const float4 CY = lb4[1 * (N / 4) + w];
    const float4 C0 = cl4[2 * w + 0];      // cls[...,1] of n=4w,4w+1 = .y,.w
    const float4 C1 = cl4[2 * w + 1];      // cls[...,1] of n=4w+2,4w+3
    const int4   LC = lc4[w];
    const float x1v[4] = {X1.x, X1.y, X1.z, X1.w};
    const float y1v[4] = {Y1.x, Y1.y, Y1.z, Y1.w};
    const float x2v[4] = {X2.x, X2.y, X2.z, X2.w};
    const float y2v[4] = {Y2.x, Y2.y, Y2.z, Y2.w};
    const float cxv[4] = {CX.x, CX.y, CX.z, CX.w};
    const float cyv[4] = {CY.x, CY.y, CY.z, CY.w};
    const float clv[4] = {C0.y, C0.w, C1.y, C1.w};
    const int   lcv[4] = {LC.x, LC.y, LC.z, LC.w};
#pragma unroll
    for (int c = 0; c < 4; ++c) {
      const int k = h * 4 + c;
      float x1 = x1v[c], y1 = y1v[c], x2 = x2v[c], y2 = y2v[c];
      float ww = fmaxf(fminf(tx2, x2) - fmaxf(tx1, x1), 0.f);
      float hh = fmaxf(fminf(ty2, y2) - fmaxf(ty1, y1), 0.f);
      float inter = ww * hh;
      float iou  = inter / ((x2 - x1) * (y2 - y1) + ta - inter);
      float prob = __expf(clv[c]);
      bool  pos  = lcv[c] > 0;
      float cx = cxv[c] + tx1, cy = cyv[c] + ty1;
      float dx = cx - tcx, dy = cy - tcy;
      di[k]  = sqrtf(dx * dx + dy * dy);
      v1i[k] = pos ? __expf(-G1 * prob) : 0.f;   // >0 iff pos
      v2i[k] = pos ? __expf(-G2 * iou)  : 0.f;
    }
  }
  __syncthreads();

  // ---- rank-sort + inclusive suffix sums (wave 0) ----
  if (t < TJ) {
    const unsigned long long mykey = ((unsigned long long)uj << 32) | (unsigned)t;
    int rank = 0; float s1 = 0.f, s2 = 0.f;
#pragma unroll 8
    for (int q = 0; q < TJ; ++q) {
      uint4 v = stile[q];                      // LDS broadcast
      unsigned long long kq = ((unsigned long long)v.x << 32) | v.y;
      bool lt = kq < mykey;
      rank += lt ? 1 : 0;
      s1 += lt ? 0.f : __uint_as_float(v.z);
      s2 += lt ? 0.f : __uint_as_float(v.w);
    }
    ssd[rank] = dm_j; suf1[rank] = s1; suf2[rank] = s2;    // bijective fill
  }
  __syncthreads();

  // ---- 8 binary searches + suffix lookups (exact monotone f32 predicate) ----
  double p1 = 0.0, p2 = 0.0; int cnt = 0;
#pragma unroll
  for (int k = 0; k < IPT; ++k) {
    const float d = di[k];
    int kk = 0;
#pragma unroll
    for (int w = TJ >> 1; w > 0; w >>= 1)
      kk += (ssd[kk + w - 1] - d >= 1.0f) ? 0 : w;
    kk += (ssd[kk] - d >= 1.0f) ? 0 : 1;       // kk in [0, TJ]
    p1 += (double)v1i[k] * (double)suf1[kk];
    p2 += (double)v2i[k] * (double)suf2[kk];
    cnt += (v1i[k] > 0.f) ? (TJ - kk) : 0;
  }
  double pc = (double)cnt;

  for (int off = 32; off; off >>= 1) {
    p1 += __shfl_down(p1, off);
    p2 += __shfl_down(p2, off);
    pc += __shfl_down(pc, off);
  }
  const int wv = t >> 6, lane = t & 63;
  if (lane == 0) { red[0][wv] = p1; red[1][wv] = p2; red[2][wv] = pc; }
  __syncthreads();
  if (t == 0) {
    part[(size_t)bid * 3 + 0] = red[0][0] + red[0][1] + red[0][2] + red[0][3];
    part[(size_t)bid * 3 + 1] = red[1][0] + red[1][1] + red[1][2] + red[1][3];
    part[(size_t)bid * 3 + 2] = red[2][0] + red[2][1] + red[2][2] + red[2][3];
  }
}

__global__ void finalize_kernel(const double* __restrict__ part,
                                const int* __restrict__ dataset_id,
                                float* __restrict__ out) {
  __shared__ double sl1[B], sl2[B], sv[B];
  int t = threadIdx.x;
  int b = t >> 4, k = t & 15;             // 16 threads per batch

  double s1 = 0, s2 = 0, sc = 0;
#pragma unroll
  for (int q = 0; q < JCH; q += 16) {     // 32 partials per batch, 2 each
    size_t idx = (size_t)(b * JCH + k + q) * 3;
    s1 += part[idx]; s2 += part[idx + 1]; sc += part[idx + 2];
  }
  for (int off = 8; off; off >>= 1) {
    s1 += __shfl_down(s1, off, 16);
    s2 += __shfl_down(s2, off, 16);
    sc += __shfl_down(sc, off, 16);
  }
  if (k == 0) {
    double denom = fmax(sc, 1.0);
    bool valid = (dataset_id[b] != 1) && (sc > 0.0);
    sl1[b] = valid ? s1 / denom : 0.0;
    sl2[b] = valid ? s2 / denom : 0.0;
    sv[b]  = valid ? 1.0 : 0.0;
  }
  __syncthreads();
  if (t == 0) {
    double nv = 0, f1 = 0, f2 = 0;
    for (int bb = 0; bb < B; ++bb) { nv += sv[bb]; f1 += sl1[bb]; f2 += sl2[bb]; }
    out[0] = (float)((nv > 0) ? f1 / nv : 0.0);
    out[1] = (float)((nv > 0) ? f2 / nv : 0.0);
  }
}

extern "C" void kernel_launch(void* const* d_in, const int* in_sizes, int n_in,
                              void* d_out, int out_size, void* d_ws, size_t ws_size,
                              hipStream_t stream) {
  const float* cls       = (const float*)d_in[0];
  const int*   label_cls = (const int*)d_in[1];
  const float* label_loc = (const float*)d_in[2];
  const float* pred      = (const float*)d_in[3];
  const float* tgt       = (const float*)d_in[4];
  const int*   dset      = (const int*)d_in[5];

  double* part = (double*)d_ws;           // NBLK*3 doubles = 12 KB; every slot
                                          // written by K1 before K2 reads ->
                                          // poison-safe, stream-ordered.

  pair_kernel<<<NBLK, 256, 0, stream>>>(cls, label_cls, label_loc, pred, tgt, part);
  finalize_kernel<<<1, 256, 0, stream>>>(part, dset, (float*)d_out);
}

// Round 9
// 16.706 us; speedup vs baseline: 1.3771x; 1.1358x over previous
//
#include <hip/hip_runtime.h>

// Rank IGR Loss — two kernels, no device-scope sync (fences/atomics cost
// ~20us on XCD-noncoherent L2 — R3/R4 lesson). This is the measured-best
// configuration (R5: 16.6us, absmax 0.0), reproduced verbatim after R6-R8
// alternatives (single-kernel atomic tails, block-halving, vectorized
// loads) all measured slower.
//
// K1 (1024 blocks): per-block sorted 64-elem j-tile + inclusive suffix sums
//   of w1=e^{G1 p}, w2=e^{G2 iou}; each thread binary-searches for its 4
//   i-elems with the EXACT brute-force f32 predicate (d_j - d_i >= 1.0f,
//   monotone in d_j) and accumulates suffix lookups. Non-pos j are masked to
//   d'=-1e30 (sort to front, never satisfy); non-pos i have v1=v2=0.
// K2 (1 block): reduce 64 double-triples per batch, batch-mean the valid ones.

#define G1 3.0f
#define G2 1.0f

constexpr int B    = 16;
constexpr int N    = 2048;
constexpr int TJ   = 64;         // sorted j-tile per block
constexpr int IPT  = 4;          // i per thread
constexpr int TI   = 1024;       // i-strip per block
constexpr int ICH  = N / TI;     // 2
constexpr int JCH  = N / TJ;     // 32
constexpr int PB   = ICH * JCH;  // 64 partial-triples per batch
constexpr int NBLK = B * PB;     // 1024

__global__ void __launch_bounds__(256)
pair_kernel(const float* __restrict__ cls, const int* __restrict__ label_cls,
            const float* __restrict__ label_loc, const float* __restrict__ pred,
            const float* __restrict__ tgt, double* __restrict__ part) {
  __shared__ uint4  stile[TJ];            // {ordkey(d'), idx, w1 bits, w2 bits}
  __shared__ float  ssd[TJ];              // sorted d'
  __shared__ float  suf1[TJ + 1], suf2[TJ + 1];  // inclusive suffix sums, [TJ]=0
  __shared__ double red[3][4];

  const int bid = blockIdx.x;
  const int b   = bid >> 6;               // 64 blocks per batch
  const int r   = bid & 63;
  const int ic  = r >> 5;
  const int jc  = r & 31;
  const int t   = threadIdx.x;
  const int base = b * N;

  const float tx1 = tgt[b * 4 + 0], ty1 = tgt[b * 4 + 1];
  const float tx2 = tgt[b * 4 + 2], ty2 = tgt[b * 4 + 3];
  const float ta  = (tx2 - tx1) * (ty2 - ty1);
  const float tcx = (tx1 + tx2) * 0.5f, tcy = (ty1 + ty2) * 0.5f;

  const float* __restrict__ pb = pred      + (size_t)b * 4 * N;
  const float* __restrict__ lb = label_loc + (size_t)b * 4 * N;

  auto elem = [&](int n, float& d, float& prob, float& iou, bool& pos) {
    float x1 = pb[n], y1 = pb[N + n], x2 = pb[2 * N + n], y2 = pb[3 * N + n];
    float ww = fmaxf(fminf(tx2, x2) - fmaxf(tx1, x1), 0.f);
    float hh = fmaxf(fminf(ty2, y2) - fmaxf(ty1, y1), 0.f);
    float inter = ww * hh;
    iou  = inter / ((x2 - x1) * (y2 - y1) + ta - inter);
    prob = __expf(cls[((size_t)(base + n)) * 2 + 1]);
    pos  = label_cls[base + n] > 0;
    float cx = lb[n] + tx1, cy = lb[N + n] + ty1;
    float dx = cx - tcx, dy = cy - tcy;
    d = sqrtf(dx * dx + dy * dy);
  };

  // ---- stage j tile (wave 0) ----
  float dm_j = 0.f; unsigned uj = 0u;
  if (t < TJ) {
    float d, prob, iou; bool pos;
    elem(jc * TJ + t, d, prob, iou, pos);
    dm_j = pos ? d : -1e30f;               // !pos can never satisfy cond
    uj = __float_as_uint(dm_j);
    uj ^= (uj & 0x80000000u) ? 0xFFFFFFFFu : 0x80000000u;  // order-preserving
    stile[t] = make_uint4(uj, (unsigned)t,
                          __float_as_uint(__expf(G1 * prob)),
                          __float_as_uint(__expf(G2 * iou)));
  }
  if (t == TJ) { suf1[TJ] = 0.f; suf2[TJ] = 0.f; }

  // ---- per-thread i data (waves 1-3 overlap the j staging) ----
  float di[IPT], v1i[IPT], v2i[IPT];
#pragma unroll
  for (int k = 0; k < IPT; ++k) {
    float d, prob, iou; bool pos;
    elem(ic * TI + k * 256 + t, d, prob, iou, pos);
    di[k]  = d;
    v1i[k] = pos ? __expf(-G1 * prob) : 0.f;   // >0 iff pos
    v2i[k] = pos ? __expf(-G2 * iou)  : 0.f;
  }
  __syncthreads();

  // ---- rank-sort + inclusive suffix sums (wave 0, one 64-compare loop) ----
  if (t < TJ) {
    const unsigned long long mykey = ((unsigned long long)uj << 32) | (unsigned)t;
    int rank = 0; float s1 = 0.f, s2 = 0.f;
#pragma unroll 8
    for (int q = 0; q < TJ; ++q) {
      uint4 v = stile[q];                  // LDS broadcast
      unsigned long long kq = ((unsigned long long)v.x << 32) | v.y;
      bool lt = kq < mykey;
      rank += lt ? 1 : 0;
      s1 += lt ? 0.f : __uint_as_float(v.z);
      s2 += lt ? 0.f : __uint_as_float(v.w);
    }
    ssd[rank] = dm_j; suf1[rank] = s1; suf2[rank] = s2;   // rank is a bijection
  }
  __syncthreads();

  // ---- 4 binary searches + suffix lookups ----
  double p1 = 0.0, p2 = 0.0; int cnt = 0;
#pragma unroll
  for (int k = 0; k < IPT; ++k) {
    const float d = di[k];
    int kk = 0;
#pragma unroll
    for (int w = TJ >> 1; w > 0; w >>= 1)       // exact monotone f32 predicate
      kk += (ssd[kk + w - 1] - d >= 1.0f) ? 0 : w;
    kk += (ssd[kk] - d >= 1.0f) ? 0 : 1;        // kk in [0, TJ]
    p1 += (double)v1i[k] * (double)suf1[kk];
    p2 += (double)v2i[k] * (double)suf2[kk];
    cnt += (v1i[k] > 0.f) ? (TJ - kk) : 0;      // suffix is all pos & cond
  }
  double pc = (double)cnt;

  for (int off = 32; off; off >>= 1) {
    p1 += __shfl_down(p1, off);
    p2 += __shfl_down(p2, off);
    pc += __shfl_down(pc, off);
  }
  const int wv = t >> 6, lane = t & 63;
  if (lane == 0) { red[0][wv] = p1; red[1][wv] = p2; red[2][wv] = pc; }
  __syncthreads();
  if (t == 0) {
    part[(size_t)bid * 3 + 0] = red[0][0] + red[0][1] + red[0][2] + red[0][3];
    part[(size_t)bid * 3 + 1] = red[1][0] + red[1][1] + red[1][2] + red[1][3];
    part[(size_t)bid * 3 + 2] = red[2][0] + red[2][1] + red[2][2] + red[2][3];
  }
}

__global__ void finalize_kernel(const double* __restrict__ part,
                                const int* __restrict__ dataset_id,
                                float* __restrict__ out) {
  __shared__ double sl1[B], sl2[B], sv[B];
  int t = threadIdx.x;
  int b = t >> 4, k = t & 15;             // 16 threads per batch

  double s1 = 0, s2 = 0, sc = 0;
#pragma unroll
  for (int q = 0; q < PB; q += 16) {
    size_t idx = (size_t)(b * PB + k + q) * 3;
    s1 += part[idx]; s2 += part[idx + 1]; sc += part[idx + 2];
  }
  for (int off = 8; off; off >>= 1) {
    s1 += __shfl_down(s1, off, 16);
    s2 += __shfl_down(s2, off, 16);
    sc += __shfl_down(sc, off, 16);
  }
  if (k == 0) {
    double denom = fmax(sc, 1.0);
    bool valid = (dataset_id[b] != 1) && (sc > 0.0);
    sl1[b] = valid ? s1 / denom : 0.0;
    sl2[b] = valid ? s2 / denom : 0.0;
    sv[b]  = valid ? 1.0 : 0.0;
  }
  __syncthreads();
  if (t == 0) {
    double nv = 0, f1 = 0, f2 = 0;
    for (int bb = 0; bb < B; ++bb) { nv += sv[bb]; f1 += sl1[bb]; f2 += sl2[bb]; }
    out[0] = (float)((nv > 0) ? f1 / nv : 0.0);
    out[1] = (float)((nv > 0) ? f2 / nv : 0.0);
  }
}

extern "C" void kernel_launch(void* const* d_in, const int* in_sizes, int n_in,
                              void* d_out, int out_size, void* d_ws, size_t ws_size,
                              hipStream_t stream) {
  const float* cls       = (const float*)d_in[0];
  const int*   label_cls = (const int*)d_in[1];
  const float* label_loc = (const float*)d_in[2];
  const float* pred      = (const float*)d_in[3];
  const float* tgt       = (const float*)d_in[4];
  const int*   dset      = (const int*)d_in[5];

  double* part = (double*)d_ws;           // NBLK*3 doubles = 24 KB

  pair_kernel<<<NBLK, 256, 0, stream>>>(cls, label_cls, label_loc, pred, tgt, part);
  finalize_kernel<<<1, 256, 0, stream>>>(part, dset, (float*)d_out);
}